// Round 3
// baseline (725.957 us; speedup 1.0000x reference)
//
#include <hip/hip_runtime.h>
#include <math.h>
#include <stdint.h>
#include <stddef.h>

typedef _Float16 f16;
typedef _Float16 f16x8 __attribute__((ext_vector_type(8)));
typedef _Float16 f16x4 __attribute__((ext_vector_type(4)));
typedef __fp16 fp16x2 __attribute__((ext_vector_type(2)));
typedef float f32x4 __attribute__((ext_vector_type(4)));
typedef float fvec4 __attribute__((ext_vector_type(4)));
typedef unsigned int u32x4 __attribute__((ext_vector_type(4)));

#define MFMA16F16(a, b, c) __builtin_amdgcn_mfma_f32_16x16x32_f16((a), (b), (c), 0, 0, 0)

static constexpr int kT = 2048;
static constexpr int kB = 4;
static constexpr int kD = 1024;
static constexpr int kNH = 16;
static constexpr int kM = kB * kT;  // 8192
static constexpr int kMAXL = 100;
static constexpr float kLOG2E = 1.4426950408889634f;

// ---------------- workspace layout (bytes) ----------------
static constexpr size_t SZ_XH = (size_t)kM * kD * 2;  // 16 MB fp16
static constexpr size_t SZ_W = (size_t)kD * kD * 2;   // 2 MB fp16
static constexpr size_t OFF_TAB = 0;                  // 16*101 floats + (1-w)
static constexpr size_t OFF_XH = 8192;
static constexpr size_t OFF_WQ = OFF_XH + SZ_XH;
static constexpr size_t OFF_WK = OFF_WQ + SZ_W;
static constexpr size_t OFF_WV = OFF_WK + SZ_W;
static constexpr size_t OFF_WF = OFF_WV + SZ_W;
static constexpr size_t OFF_Q = OFF_WF + SZ_W;
static constexpr size_t OFF_K = OFF_Q + SZ_XH;
static constexpr size_t OFF_V = OFF_K + SZ_XH;   // holds V^T [1024][8192]
static constexpr size_t OFF_P = OFF_V + SZ_XH;   // blended (blend@V) fp16
static constexpr size_t WS_NEED = OFF_P + SZ_XH; // ~92 MB

// async global->LDS 16B (gfx950). LDS dest must be wave-uniform base + lane*16;
// all call sites map thread tid -> lds byte offset tid*16, satisfying this.
__device__ __forceinline__ void gl2lds16(const f16* g, f16* l) {
  auto gp = reinterpret_cast<const __attribute__((address_space(1))) void*>(
      reinterpret_cast<uintptr_t>(g));
  auto lp = reinterpret_cast<__attribute__((address_space(3))) void*>(
      reinterpret_cast<uintptr_t>(l));
  __builtin_amdgcn_global_load_lds(gp, lp, 16, 0, 0);
}

__device__ __forceinline__ unsigned int pk_f16(float a, float b) {
  fp16x2 h = __builtin_amdgcn_cvt_pkrtz(a, b);
  return __builtin_bit_cast(unsigned int, h);
}

// ---------------- P table: tab[h][L] = w * P_value(h, L), plus (1-w) ----------------
__global__ void mk_tab_kernel(const float* __restrict__ mu, const float* __restrict__ lam,
                              const float* __restrict__ g1, const float* __restrict__ g2,
                              const float* __restrict__ th1, const float* __restrict__ th2,
                              float* __restrict__ tab) {
  const float w = 1.0f / (1.0f + expf(-mu[0]));
  for (int e = threadIdx.x; e < kNH * (kMAXL + 1); e += blockDim.x) {
    const int h = e / (kMAXL + 1);
    const int L = e - h * (kMAXL + 1);
    const float Lf = (float)L;
    float v;
    if (h < 4) {
      const float base = lam[h];
      const float mag = expf(Lf * logf(fabsf(base)));
      const float sgn = (base < 0.0f && (L & 1)) ? -1.0f : 1.0f;
      v = mag * sgn;
    } else if (h < 10) {
      const int s = h - 4;
      v = expf(Lf * logf(g1[s])) * sinf(th1[s] * Lf);
    } else {
      const int s = h - 10;
      v = expf(Lf * logf(g2[s])) * cosf(th2[s] * Lf);
    }
    tab[e] = w * v;
  }
  if (threadIdx.x == 0) tab[kNH * (kMAXL + 1)] = 1.0f - w;
}

// ---------------- fp32 -> fp16 convert ----------------
__global__ void cvt_kernel(const float* __restrict__ s, f16* __restrict__ d, int n4) {
  int i = blockIdx.x * blockDim.x + threadIdx.x;
  const int stride = gridDim.x * blockDim.x;
  for (; i < n4; i += stride) {
    fvec4 v = ((const fvec4*)s)[i];
    f16x4 o;
    o[0] = (f16)v[0]; o[1] = (f16)v[1]; o[2] = (f16)v[2]; o[3] = (f16)v[3];
    ((f16x4*)d)[i] = o;
  }
}

// ---------------- C[m,n] = sum_k A[m,k]*B[n,k] (+bias) * oscale ----------------
// 128x128 tile, BK=32, 4 waves each 64x64, 16x16x32 f16 MFMA.
// m97-style: async global_load_lds staging, 2-barrier K-loop.
template <typename OutT, bool BIAS_ROW>
__global__ __launch_bounds__(256, 2) void gemm_bt_kernel(
    const f16* __restrict__ A, const f16* __restrict__ B, const float* __restrict__ bias,
    OutT* __restrict__ C, int M, int N, int K, float oscale) {
  __shared__ f16 As[128][32];
  __shared__ f16 Bs[128][32];
  const int tid = threadIdx.x;
  const int lane = tid & 63;
  const int wave = tid >> 6;
  const int quad = lane >> 4;
  const int l16 = lane & 15;
  const int nb = N >> 7;
  const int bm = blockIdx.x / nb;
  const int bn = blockIdx.x - bm * nb;
  const int m0 = bm << 7;
  const int n0 = bn << 7;
  const int wm = (wave & 1) << 6;
  const int wn = (wave >> 1) << 6;

  const int srow = tid >> 2;        // 0..63
  const int scol = (tid & 3) << 3;  // 0,8,16,24 -> lds byte off = tid*16
  const f16* Ap = A + (size_t)(m0 + srow) * K + scol;
  const f16* Bp = B + (size_t)(n0 + srow) * K + scol;
  const size_t rstep = (size_t)64 * K;
  f16* lA0 = &As[srow][scol];
  f16* lA1 = &As[srow + 64][scol];
  f16* lB0 = &Bs[srow][scol];
  f16* lB1 = &Bs[srow + 64][scol];

  f32x4 acc[4][4];
#pragma unroll
  for (int i = 0; i < 4; i++)
#pragma unroll
    for (int j = 0; j < 4; j++) acc[i][j] = (f32x4){0.f, 0.f, 0.f, 0.f};

  for (int k0 = 0; k0 < K; k0 += 32) {
    __syncthreads();  // prev compute done before overwrite
    gl2lds16(Ap + k0, lA0);
    gl2lds16(Ap + rstep + k0, lA1);
    gl2lds16(Bp + k0, lB0);
    gl2lds16(Bp + rstep + k0, lB1);
    __syncthreads();  // compiler drains vmcnt before barrier -> tiles visible
    f16x8 af[4], bf[4];
#pragma unroll
    for (int i = 0; i < 4; i++) af[i] = *(const f16x8*)&As[wm + i * 16 + l16][quad * 8];
#pragma unroll
    for (int i = 0; i < 4; i++) bf[i] = *(const f16x8*)&Bs[wn + i * 16 + l16][quad * 8];
#pragma unroll
    for (int mi = 0; mi < 4; mi++)
#pragma unroll
      for (int ni = 0; ni < 4; ni++) acc[mi][ni] = MFMA16F16(af[mi], bf[ni], acc[mi][ni]);
  }

#pragma unroll
  for (int mi = 0; mi < 4; mi++) {
    const int rbase = m0 + wm + mi * 16 + quad * 4;
#pragma unroll
    for (int ni = 0; ni < 4; ni++) {
      const int gc = n0 + wn + ni * 16 + l16;
      const float bcol = BIAS_ROW ? 0.0f : bias[gc];
#pragma unroll
      for (int r = 0; r < 4; r++) {
        const int gr = rbase + r;
        float v = acc[mi][ni][r] + (BIAS_ROW ? bias[gr] : bcol);
        v *= oscale;
        C[(size_t)gr * N + gc] = (OutT)v;
      }
    }
  }
}

// ---------------- fused attention + positional blend (S^T formulation) ----------------
// grid: 16 q-tiles x 16 heads x 4 batches. 4 waves/block, each wave owns 32 q rows.
// S^T = K @ Q^T so softmax reduces over regs+quads and the PV A-fragment is built by an
// in-register cross-quad exchange (no LDS round-trip). P = blend positional matrix:
//   tiles with j0+228 <= q0 are all tab[100] -> splat-fragment MFMA into row-independent
//   Opc[4]; the <=2 near-diagonal tiles are handled post-loop with table fragments.
__global__ __launch_bounds__(256, 3) void attn_kernel(
    const f16* __restrict__ Qh, const f16* __restrict__ Kh, const f16* __restrict__ Vt,
    const float* __restrict__ tabg, f16* __restrict__ Pb) {
  __shared__ f16 Ks[128][72];   // K tile [j][d], +8 pad
  __shared__ f16 Vs[64][136];   // V^T tile [d][j], +8 pad
  __shared__ float tab_s[101];

  const int tid = threadIdx.x;
  const int lane = tid & 63;
  const int wave = tid >> 6;
  const int qd = lane >> 4;
  const int l16 = lane & 15;
  const int qt = blockIdx.x & 15;
  const int h = (blockIdx.x >> 4) & 15;
  const int bi = blockIdx.x >> 8;

  if (tid < 101) tab_s[tid] = tabg[h * 101 + tid];
  const float one_m_w = tabg[kNH * 101];
  const float tab100f = tabg[h * 101 + kMAXL];  // from global: no barrier needed

  const int qblk = qt * 128;
  const int q0 = qblk + wave * 32;  // t-local
  const size_t bt0 = (size_t)bi * kT;

  // Q fragments (B-operand layout) straight from global; live whole kernel
  f16x8 qf[2][2];
#pragma unroll
  for (int mi = 0; mi < 2; mi++)
#pragma unroll
    for (int kc = 0; kc < 2; kc++)
      qf[mi][kc] =
          *(const f16x8*)(Qh + (bt0 + q0 + mi * 16 + l16) * kD + h * 64 + kc * 32 + qd * 8);

  f32x4 Oa[2][4];   // attention accumulator (C-layout: row=q, col=d)
  f32x4 Opc[4];     // const-region P@V (row-independent -> one m-tile)
#pragma unroll
  for (int nt = 0; nt < 4; nt++) {
    Oa[0][nt] = (f32x4){0.f, 0.f, 0.f, 0.f};
    Oa[1][nt] = (f32x4){0.f, 0.f, 0.f, 0.f};
    Opc[nt] = (f32x4){0.f, 0.f, 0.f, 0.f};
  }
  float mrow[2] = {-INFINITY, -INFINITY};
  float lrow[2] = {0.f, 0.f};

  const int sr8 = tid >> 3, sp8 = tid & 7;
  const int sr16 = tid >> 4, sp16 = tid & 15;
  const int lA = ((qd & 1) << 5) + l16;  // src lane (quad 2*(qd&1), same l16)
  const int lB = lA + 16;
  const bool hiT = qd >= 2;

  f16x8 cf;  // splat tab[100] fragment
  {
    const f16 cth = (f16)tab100f;
#pragma unroll
    for (int ii = 0; ii < 8; ii++) cf[ii] = cth;
  }

  for (int j0 = 0; j0 < kT; j0 += 128) {
    __syncthreads();
    // stage K tile
#pragma unroll
    for (int u = 0; u < 4; u++) {
      const int jr = sr8 + u * 32;
      *(f16x8*)&Ks[jr][sp8 * 8] = *(const f16x8*)(Kh + (bt0 + j0 + jr) * kD + h * 64 + sp8 * 8);
    }
    // stage V^T tile
#pragma unroll
    for (int u = 0; u < 4; u++) {
      const int d = sr16 + u * 16;
      *(f16x8*)&Vs[d][sp16 * 8] =
          *(const f16x8*)(Vt + (size_t)(h * 64 + d) * kM + bt0 + j0 + sp16 * 8);
    }
    __syncthreads();

#pragma unroll
    for (int c = 0; c < 2; c++) {  // 64-j chunks
      // S^T = K Q^T : rows j (4 m-tiles), cols q (2 n-tiles)
      f32x4 s[2][4];
#pragma unroll
      for (int mi = 0; mi < 2; mi++)
#pragma unroll
        for (int ni = 0; ni < 4; ni++) s[mi][ni] = (f32x4){0.f, 0.f, 0.f, 0.f};
#pragma unroll
      for (int kc = 0; kc < 2; kc++) {
#pragma unroll
        for (int ni = 0; ni < 4; ni++) {
          f16x8 kf = *(const f16x8*)&Ks[c * 64 + ni * 16 + l16][kc * 32 + qd * 8];
          s[0][ni] = MFMA16F16(kf, qf[0][kc], s[0][ni]);
          s[1][ni] = MFMA16F16(kf, qf[1][kc], s[1][ni]);
        }
      }

      unsigned int pk2[2][4][2];
#pragma unroll
      for (int mi = 0; mi < 2; mi++) {
        // column (q) max over regs + quads
        float mx = s[mi][0][0];
#pragma unroll
        for (int ni = 0; ni < 4; ni++)
#pragma unroll
          for (int r = 0; r < 4; r++) mx = fmaxf(mx, s[mi][ni][r]);
        mx = fmaxf(mx, __shfl_xor(mx, 16));
        mx = fmaxf(mx, __shfl_xor(mx, 32));
        const float mnew = fmaxf(mrow[mi], mx);
        const float al = __builtin_amdgcn_exp2f(mrow[mi] - mnew);
        mrow[mi] = mnew;
        // rescale Oa rows (alpha indexed by q=l16 -> fetch per C-row qd*4+r)
        float ar[4];
#pragma unroll
        for (int r = 0; r < 4; r++) ar[r] = __shfl(al, qd * 4 + r);
#pragma unroll
        for (int nt = 0; nt < 4; nt++)
#pragma unroll
          for (int r = 0; r < 4; r++) Oa[mi][nt][r] *= ar[r];
        // exp2 + pack + row-sum
        float lsum = 0.f;
#pragma unroll
        for (int ni = 0; ni < 4; ni++) {
          const float e0 = __builtin_amdgcn_exp2f(s[mi][ni][0] - mnew);
          const float e1 = __builtin_amdgcn_exp2f(s[mi][ni][1] - mnew);
          const float e2 = __builtin_amdgcn_exp2f(s[mi][ni][2] - mnew);
          const float e3 = __builtin_amdgcn_exp2f(s[mi][ni][3] - mnew);
          lsum += (e0 + e1) + (e2 + e3);
          pk2[mi][ni][0] = pk_f16(e0, e1);
          pk2[mi][ni][1] = pk_f16(e2, e3);
        }
        lsum += __shfl_xor(lsum, 16);
        lsum += __shfl_xor(lsum, 32);
        lrow[mi] = lrow[mi] * al + lsum;
      }

      // exchange C-layout exp(S^T) -> A-fragments, then O += P @ V
#pragma unroll
      for (int kc2 = 0; kc2 < 2; kc2++) {
        f16x8 af[2];
#pragma unroll
        for (int mi = 0; mi < 2; mi++) {
          const unsigned int a0 = __shfl(pk2[mi][2 * kc2][0], lA);
          const unsigned int a1 = __shfl(pk2[mi][2 * kc2][1], lA);
          const unsigned int a2 = __shfl(pk2[mi][2 * kc2][0], lB);
          const unsigned int a3 = __shfl(pk2[mi][2 * kc2][1], lB);
          const unsigned int b0 = __shfl(pk2[mi][2 * kc2 + 1][0], lA);
          const unsigned int b1 = __shfl(pk2[mi][2 * kc2 + 1][1], lA);
          const unsigned int b2 = __shfl(pk2[mi][2 * kc2 + 1][0], lB);
          const unsigned int b3 = __shfl(pk2[mi][2 * kc2 + 1][1], lB);
          u32x4 u;
          u[0] = hiT ? b0 : a0;
          u[1] = hiT ? b1 : a1;
          u[2] = hiT ? b2 : a2;
          u[3] = hiT ? b3 : a3;
          af[mi] = __builtin_bit_cast(f16x8, u);
        }
#pragma unroll
        for (int nt = 0; nt < 4; nt++) {
          f16x8 vf = *(const f16x8*)&Vs[nt * 16 + l16][c * 64 + kc2 * 32 + qd * 8];
          Oa[0][nt] = MFMA16F16(af[0], vf, Oa[0][nt]);
          Oa[1][nt] = MFMA16F16(af[1], vf, Oa[1][nt]);
        }
      }
    }

    // constant positional region: whole tile is tab[100]
    if (j0 + 228 <= q0) {
#pragma unroll
      for (int kc = 0; kc < 4; kc++)
#pragma unroll
        for (int nt = 0; nt < 4; nt++) {
          f16x8 vf = *(const f16x8*)&Vs[nt * 16 + l16][kc * 32 + qd * 8];
          Opc[nt] = MFMA16F16(cf, vf, Opc[nt]);
        }
    }
  }

  // scale attention by (1-w)/l and fold in const-P (row-independent)
#pragma unroll
  for (int mi = 0; mi < 2; mi++) {
    float lr[4];
#pragma unroll
    for (int r = 0; r < 4; r++) lr[r] = __shfl(lrow[mi], qd * 4 + r);
#pragma unroll
    for (int nt = 0; nt < 4; nt++)
#pragma unroll
      for (int r = 0; r < 4; r++)
        Oa[mi][nt][r] = Oa[mi][nt][r] * (one_m_w / lr[r]) + Opc[nt][r];
  }

  // near-diagonal positional band: restage the two boundary V tiles, table fragments
#pragma unroll
  for (int tb = 0; tb < 2; tb++) {
    const int jb = qblk - 128 + tb * 128;  // block-uniform
    if (jb >= 0) {
      __syncthreads();
#pragma unroll
      for (int u = 0; u < 4; u++) {
        const int d = sr16 + u * 16;
        *(f16x8*)&Vs[d][sp16 * 8] =
            *(const f16x8*)(Vt + (size_t)(h * 64 + d) * kM + bt0 + jb + sp16 * 8);
      }
      __syncthreads();
#pragma unroll
      for (int kc = 0; kc < 4; kc++) {
        f16x8 wf[2];
#pragma unroll
        for (int mi = 0; mi < 2; mi++) {
          const int q = q0 + mi * 16 + l16;
#pragma unroll
          for (int jj = 0; jj < 8; jj++) {
            const int j = jb + kc * 32 + qd * 8 + jj;
            const int dlt = q - j;
            float pv = 0.0f;
            if (dlt > 0) pv = tab_s[dlt > kMAXL ? kMAXL : dlt];
            wf[mi][jj] = (f16)pv;
          }
        }
#pragma unroll
        for (int nt = 0; nt < 4; nt++) {
          f16x8 vf = *(const f16x8*)&Vs[nt * 16 + l16][kc * 32 + qd * 8];
          Oa[0][nt] = MFMA16F16(wf[0], vf, Oa[0][nt]);
          Oa[1][nt] = MFMA16F16(wf[1], vf, Oa[1][nt]);
        }
      }
    }
  }

  // store
#pragma unroll
  for (int mi = 0; mi < 2; mi++)
#pragma unroll
    for (int nt = 0; nt < 4; nt++)
#pragma unroll
      for (int r = 0; r < 4; r++) {
        const int q = q0 + mi * 16 + qd * 4 + r;
        Pb[(bt0 + q) * kD + h * 64 + nt * 16 + l16] = (f16)Oa[mi][nt][r];
      }
}

extern "C" void kernel_launch(void* const* d_in, const int* in_sizes, int n_in, void* d_out,
                              int out_size, void* d_ws, size_t ws_size, hipStream_t stream) {
  const float* x = (const float*)d_in[0];
  const float* mu = (const float*)d_in[1];
  const float* lam = (const float*)d_in[2];
  const float* g1 = (const float*)d_in[3];
  const float* g2 = (const float*)d_in[4];
  const float* th1 = (const float*)d_in[5];
  const float* th2 = (const float*)d_in[6];
  const float* Wq = (const float*)d_in[7];
  const float* bq = (const float*)d_in[8];
  const float* Wk = (const float*)d_in[9];
  const float* bk = (const float*)d_in[10];
  const float* Wv = (const float*)d_in[11];
  const float* bv = (const float*)d_in[12];
  const float* Wf = (const float*)d_in[13];
  const float* bf = (const float*)d_in[14];

  if (ws_size < WS_NEED) return;  // cannot run without scratch

  char* ws = (char*)d_ws;
  float* tab = (float*)(ws + OFF_TAB);
  f16* xh = (f16*)(ws + OFF_XH);
  f16* wqh = (f16*)(ws + OFF_WQ);
  f16* wkh = (f16*)(ws + OFF_WK);
  f16* wvh = (f16*)(ws + OFF_WV);
  f16* wfh = (f16*)(ws + OFF_WF);
  f16* Qp = (f16*)(ws + OFF_Q);
  f16* Kp = (f16*)(ws + OFF_K);
  f16* Vtp = (f16*)(ws + OFF_V);
  f16* Pbp = (f16*)(ws + OFF_P);

  mk_tab_kernel<<<1, 256, 0, stream>>>(mu, lam, g1, g2, th1, th2, tab);
  cvt_kernel<<<2048, 256, 0, stream>>>(x, xh, kM * kD / 4);
  cvt_kernel<<<1024, 256, 0, stream>>>(Wq, wqh, kD * kD / 4);
  cvt_kernel<<<1024, 256, 0, stream>>>(Wk, wkh, kD * kD / 4);
  cvt_kernel<<<1024, 256, 0, stream>>>(Wv, wvh, kD * kD / 4);
  cvt_kernel<<<1024, 256, 0, stream>>>(Wf, wfh, kD * kD / 4);

  // Q scaled by log2(e) (after bias) so attention softmax uses exp2 exactly.
  gemm_bt_kernel<f16, false><<<512, 256, 0, stream>>>(xh, wqh, bq, Qp, kM, kD, kD, kLOG2E);
  gemm_bt_kernel<f16, false><<<512, 256, 0, stream>>>(xh, wkh, bk, Kp, kM, kD, kD, 1.0f);
  // V^T = Wv * x^T : same kernel, swapped operands, bias indexed by row (dim)
  gemm_bt_kernel<f16, true><<<512, 256, 0, stream>>>(wvh, xh, bv, Vtp, kD, kM, kD, 1.0f);

  attn_kernel<<<1024, 256, 0, stream>>>(Qp, Kp, Vtp, tab, Pbp);

  gemm_bt_kernel<float, false><<<512, 256, 0, stream>>>(Pbp, wfh, bf, (float*)d_out, kM, kD, kD,
                                                        1.0f);
}

// Round 4
// 439.916 us; speedup vs baseline: 1.6502x; 1.6502x over previous
//
#include <hip/hip_runtime.h>
#include <math.h>
#include <stdint.h>
#include <stddef.h>

typedef _Float16 f16;
typedef _Float16 f16x8 __attribute__((ext_vector_type(8)));
typedef _Float16 f16x4 __attribute__((ext_vector_type(4)));
typedef __fp16 fp16x2 __attribute__((ext_vector_type(2)));
typedef float f32x4 __attribute__((ext_vector_type(4)));
typedef float fvec4 __attribute__((ext_vector_type(4)));
typedef unsigned int u32x4 __attribute__((ext_vector_type(4)));

#define MFMA16F16(a, b, c) __builtin_amdgcn_mfma_f32_16x16x32_f16((a), (b), (c), 0, 0, 0)

static constexpr int kT = 2048;
static constexpr int kB = 4;
static constexpr int kD = 1024;
static constexpr int kNH = 16;
static constexpr int kM = kB * kT;  // 8192
static constexpr int kMAXL = 100;
static constexpr float kLOG2E = 1.4426950408889634f;

// ---------------- workspace layout (bytes) ----------------
static constexpr size_t SZ_XH = (size_t)kM * kD * 2;  // 16 MB fp16
static constexpr size_t SZ_W = (size_t)kD * kD * 2;   // 2 MB fp16
static constexpr size_t OFF_TAB = 0;                  // 16*101 floats + (1-w)
static constexpr size_t OFF_XH = 8192;
static constexpr size_t OFF_WQ = OFF_XH + SZ_XH;
static constexpr size_t OFF_WK = OFF_WQ + SZ_W;
static constexpr size_t OFF_WV = OFF_WK + SZ_W;
static constexpr size_t OFF_WF = OFF_WV + SZ_W;
static constexpr size_t OFF_Q = OFF_WF + SZ_W;
static constexpr size_t OFF_K = OFF_Q + SZ_XH;
static constexpr size_t OFF_V = OFF_K + SZ_XH;   // holds V^T [1024][8192]
static constexpr size_t OFF_P = OFF_V + SZ_XH;   // blended (blend@V) fp16
static constexpr size_t WS_NEED = OFF_P + SZ_XH; // ~92 MB

__device__ __forceinline__ unsigned int pk_f16(float a, float b) {
  fp16x2 h = __builtin_amdgcn_cvt_pkrtz(a, b);
  return __builtin_bit_cast(unsigned int, h);
}

// ---------------- P table: tab[h][L] = w * P_value(h, L), plus (1-w) ----------------
__global__ void mk_tab_kernel(const float* __restrict__ mu, const float* __restrict__ lam,
                              const float* __restrict__ g1, const float* __restrict__ g2,
                              const float* __restrict__ th1, const float* __restrict__ th2,
                              float* __restrict__ tab) {
  const float w = 1.0f / (1.0f + expf(-mu[0]));
  for (int e = threadIdx.x; e < kNH * (kMAXL + 1); e += blockDim.x) {
    const int h = e / (kMAXL + 1);
    const int L = e - h * (kMAXL + 1);
    const float Lf = (float)L;
    float v;
    if (h < 4) {
      const float base = lam[h];
      const float mag = expf(Lf * logf(fabsf(base)));
      const float sgn = (base < 0.0f && (L & 1)) ? -1.0f : 1.0f;
      v = mag * sgn;
    } else if (h < 10) {
      const int s = h - 4;
      v = expf(Lf * logf(g1[s])) * sinf(th1[s] * Lf);
    } else {
      const int s = h - 10;
      v = expf(Lf * logf(g2[s])) * cosf(th2[s] * Lf);
    }
    tab[e] = w * v;
  }
  if (threadIdx.x == 0) tab[kNH * (kMAXL + 1)] = 1.0f - w;
}

// ---------------- fp32 -> fp16 convert ----------------
__global__ void cvt_kernel(const float* __restrict__ s, f16* __restrict__ d, int n4) {
  int i = blockIdx.x * blockDim.x + threadIdx.x;
  const int stride = gridDim.x * blockDim.x;
  for (; i < n4; i += stride) {
    fvec4 v = ((const fvec4*)s)[i];
    f16x4 o;
    o[0] = (f16)v[0]; o[1] = (f16)v[1]; o[2] = (f16)v[2]; o[3] = (f16)v[3];
    ((f16x4*)d)[i] = o;
  }
}

// ---------------- C[m,n] = sum_k A[m,k]*B[n,k] (+bias) * oscale ----------------
// 128x128 tile, BK=32, 4 waves each 64x64, 16x16x32 f16 MFMA (R1 register-prefetch
// version — reverted from R3's serial global_load_lds which lost the load/MFMA overlap).
template <typename OutT, bool BIAS_ROW>
__global__ __launch_bounds__(256, 2) void gemm_bt_kernel(
    const f16* __restrict__ A, const f16* __restrict__ B, const float* __restrict__ bias,
    OutT* __restrict__ C, int M, int N, int K, float oscale) {
  __shared__ f16 As[128][32];
  __shared__ f16 Bs[128][32];
  const int tid = threadIdx.x;
  const int lane = tid & 63;
  const int wave = tid >> 6;
  const int quad = lane >> 4;
  const int l16 = lane & 15;
  const int nb = N >> 7;
  const int bm = blockIdx.x / nb;
  const int bn = blockIdx.x - bm * nb;
  const int m0 = bm << 7;
  const int n0 = bn << 7;
  const int wm = (wave & 1) << 6;
  const int wn = (wave >> 1) << 6;

  const int srow = tid >> 2;        // 0..63
  const int scol = (tid & 3) << 3;  // 0,8,16,24
  const f16* Ap = A + (size_t)(m0 + srow) * K + scol;
  const f16* Bp = B + (size_t)(n0 + srow) * K + scol;
  const size_t rstep = (size_t)64 * K;

  f32x4 acc[4][4];
#pragma unroll
  for (int i = 0; i < 4; i++)
#pragma unroll
    for (int j = 0; j < 4; j++) acc[i][j] = (f32x4){0.f, 0.f, 0.f, 0.f};

  f16x8 ra0 = *(const f16x8*)(Ap);
  f16x8 ra1 = *(const f16x8*)(Ap + rstep);
  f16x8 rb0 = *(const f16x8*)(Bp);
  f16x8 rb1 = *(const f16x8*)(Bp + rstep);

  for (int k0 = 0; k0 < K; k0 += 32) {
    __syncthreads();
    *(f16x8*)&As[srow][scol] = ra0;
    *(f16x8*)&As[srow + 64][scol] = ra1;
    *(f16x8*)&Bs[srow][scol] = rb0;
    *(f16x8*)&Bs[srow + 64][scol] = rb1;
    __syncthreads();
    if (k0 + 32 < K) {  // prefetch next K-slab while computing
      ra0 = *(const f16x8*)(Ap + (k0 + 32));
      ra1 = *(const f16x8*)(Ap + rstep + (k0 + 32));
      rb0 = *(const f16x8*)(Bp + (k0 + 32));
      rb1 = *(const f16x8*)(Bp + rstep + (k0 + 32));
    }
    f16x8 af[4], bf[4];
#pragma unroll
    for (int i = 0; i < 4; i++) af[i] = *(const f16x8*)&As[wm + i * 16 + l16][quad * 8];
#pragma unroll
    for (int i = 0; i < 4; i++) bf[i] = *(const f16x8*)&Bs[wn + i * 16 + l16][quad * 8];
#pragma unroll
    for (int mi = 0; mi < 4; mi++)
#pragma unroll
      for (int ni = 0; ni < 4; ni++) acc[mi][ni] = MFMA16F16(af[mi], bf[ni], acc[mi][ni]);
  }

#pragma unroll
  for (int mi = 0; mi < 4; mi++) {
    const int rbase = m0 + wm + mi * 16 + quad * 4;
#pragma unroll
    for (int ni = 0; ni < 4; ni++) {
      const int gc = n0 + wn + ni * 16 + l16;
      const float bcol = BIAS_ROW ? 0.0f : bias[gc];
#pragma unroll
      for (int r = 0; r < 4; r++) {
        const int gr = rbase + r;
        float v = acc[mi][ni][r] + (BIAS_ROW ? bias[gr] : bcol);
        v *= oscale;
        C[(size_t)gr * N + gc] = (OutT)v;
      }
    }
  }
}

// ---------------- fused attention + positional blend (S^T formulation) ----------------
// grid: 1024 blocks = 16 qt x 16 h x 4 bi, XCD-swizzled: blockIdx = xcd + 8*rest with
// xcd = (bi*16+h)&7, so all 16 q-tiles of one (bi,h) land on ONE XCD -> its 512 KB K/V
// working set stays L2-resident (8 combos/XCD = 4 MB = L2). launch_bounds(256,4):
// 36 KB LDS x 4 = 144 <= 160 KB -> all 1024 blocks co-resident, no tail wave.
__global__ __launch_bounds__(256, 4) void attn_kernel(
    const f16* __restrict__ Qh, const f16* __restrict__ Kh, const f16* __restrict__ Vt,
    const float* __restrict__ tabg, f16* __restrict__ Pb) {
  __shared__ f16 Ks[128][72];   // K tile [j][d], +8 pad
  __shared__ f16 Vs[64][136];   // V^T tile [d][j], +8 pad
  __shared__ float tab_s[101];

  const int tid = threadIdx.x;
  const int lane = tid & 63;
  const int wave = tid >> 6;
  const int qd = lane >> 4;
  const int l16 = lane & 15;
  // XCD-affinity decode
  const int xcd = blockIdx.x & 7;
  const int rest = blockIdx.x >> 3;       // 0..127
  const int qt = rest & 15;
  const int combo = (rest >> 4) * 8 + xcd;  // 0..63 == bi*16 + h
  const int h = combo & 15;
  const int bi = combo >> 4;

  if (tid < 101) tab_s[tid] = tabg[h * 101 + tid];
  const float one_m_w = tabg[kNH * 101];
  const float tab100f = tabg[h * 101 + kMAXL];  // from global: no barrier needed

  const int qblk = qt * 128;
  const int q0 = qblk + wave * 32;  // t-local
  const size_t bt0 = (size_t)bi * kT;

  // Q fragments (B-operand layout) straight from global; live whole kernel
  f16x8 qf[2][2];
#pragma unroll
  for (int mi = 0; mi < 2; mi++)
#pragma unroll
    for (int kc = 0; kc < 2; kc++)
      qf[mi][kc] =
          *(const f16x8*)(Qh + (bt0 + q0 + mi * 16 + l16) * kD + h * 64 + kc * 32 + qd * 8);

  f32x4 Oa[2][4];   // attention accumulator (C-layout: row=q, col=d)
  f32x4 Opc[4];     // const-region P@V (row-independent -> one m-tile)
#pragma unroll
  for (int nt = 0; nt < 4; nt++) {
    Oa[0][nt] = (f32x4){0.f, 0.f, 0.f, 0.f};
    Oa[1][nt] = (f32x4){0.f, 0.f, 0.f, 0.f};
    Opc[nt] = (f32x4){0.f, 0.f, 0.f, 0.f};
  }
  float mrow[2] = {-INFINITY, -INFINITY};
  float lrow[2] = {0.f, 0.f};

  const int sr8 = tid >> 3, sp8 = tid & 7;
  const int sr16 = tid >> 4, sp16 = tid & 15;
  const int lA = ((qd & 1) << 5) + l16;  // src lane (quad 2*(qd&1), same l16)
  const int lB = lA + 16;
  const bool hiT = qd >= 2;

  f16x8 cf;  // splat tab[100] fragment
  {
    const f16 cth = (f16)tab100f;
#pragma unroll
    for (int ii = 0; ii < 8; ii++) cf[ii] = cth;
  }

  for (int j0 = 0; j0 < kT; j0 += 128) {
    __syncthreads();
    // stage K tile
#pragma unroll
    for (int u = 0; u < 4; u++) {
      const int jr = sr8 + u * 32;
      *(f16x8*)&Ks[jr][sp8 * 8] = *(const f16x8*)(Kh + (bt0 + j0 + jr) * kD + h * 64 + sp8 * 8);
    }
    // stage V^T tile
#pragma unroll
    for (int u = 0; u < 4; u++) {
      const int d = sr16 + u * 16;
      *(f16x8*)&Vs[d][sp16 * 8] =
          *(const f16x8*)(Vt + (size_t)(h * 64 + d) * kM + bt0 + j0 + sp16 * 8);
    }
    __syncthreads();

#pragma unroll
    for (int c = 0; c < 2; c++) {  // 64-j chunks
      // S^T = K Q^T : rows j (4 m-tiles), cols q (2 n-tiles)
      f32x4 s[2][4];
#pragma unroll
      for (int mi = 0; mi < 2; mi++)
#pragma unroll
        for (int ni = 0; ni < 4; ni++) s[mi][ni] = (f32x4){0.f, 0.f, 0.f, 0.f};
#pragma unroll
      for (int kc = 0; kc < 2; kc++) {
#pragma unroll
        for (int ni = 0; ni < 4; ni++) {
          f16x8 kf = *(const f16x8*)&Ks[c * 64 + ni * 16 + l16][kc * 32 + qd * 8];
          s[0][ni] = MFMA16F16(kf, qf[0][kc], s[0][ni]);
          s[1][ni] = MFMA16F16(kf, qf[1][kc], s[1][ni]);
        }
      }

      unsigned int pk2[2][4][2];
#pragma unroll
      for (int mi = 0; mi < 2; mi++) {
        // column (q) max over regs + quads
        float mx = s[mi][0][0];
#pragma unroll
        for (int ni = 0; ni < 4; ni++)
#pragma unroll
          for (int r = 0; r < 4; r++) mx = fmaxf(mx, s[mi][ni][r]);
        mx = fmaxf(mx, __shfl_xor(mx, 16));
        mx = fmaxf(mx, __shfl_xor(mx, 32));
        const float mnew = fmaxf(mrow[mi], mx);
        const float al = __builtin_amdgcn_exp2f(mrow[mi] - mnew);
        mrow[mi] = mnew;
        // rescale Oa rows only when the running max actually moved
        if (__any(al < 1.0f)) {
          float ar[4];
#pragma unroll
          for (int r = 0; r < 4; r++) ar[r] = __shfl(al, qd * 4 + r);
#pragma unroll
          for (int nt = 0; nt < 4; nt++)
#pragma unroll
            for (int r = 0; r < 4; r++) Oa[mi][nt][r] *= ar[r];
        }
        // exp2 + pack + row-sum
        float lsum = 0.f;
#pragma unroll
        for (int ni = 0; ni < 4; ni++) {
          const float e0 = __builtin_amdgcn_exp2f(s[mi][ni][0] - mnew);
          const float e1 = __builtin_amdgcn_exp2f(s[mi][ni][1] - mnew);
          const float e2 = __builtin_amdgcn_exp2f(s[mi][ni][2] - mnew);
          const float e3 = __builtin_amdgcn_exp2f(s[mi][ni][3] - mnew);
          lsum += (e0 + e1) + (e2 + e3);
          pk2[mi][ni][0] = pk_f16(e0, e1);
          pk2[mi][ni][1] = pk_f16(e2, e3);
        }
        lsum += __shfl_xor(lsum, 16);
        lsum += __shfl_xor(lsum, 32);
        lrow[mi] = lrow[mi] * al + lsum;
      }

      // exchange C-layout exp(S^T) -> A-fragments, then O += P @ V
#pragma unroll
      for (int kc2 = 0; kc2 < 2; kc2++) {
        f16x8 af[2];
#pragma unroll
        for (int mi = 0; mi < 2; mi++) {
          const unsigned int a0 = __shfl(pk2[mi][2 * kc2][0], lA);
          const unsigned int a1 = __shfl(pk2[mi][2 * kc2][1], lA);
          const unsigned int a2 = __shfl(pk2[mi][2 * kc2][0], lB);
          const unsigned int a3 = __shfl(pk2[mi][2 * kc2][1], lB);
          const unsigned int b0 = __shfl(pk2[mi][2 * kc2 + 1][0], lA);
          const unsigned int b1 = __shfl(pk2[mi][2 * kc2 + 1][1], lA);
          const unsigned int b2 = __shfl(pk2[mi][2 * kc2 + 1][0], lB);
          const unsigned int b3 = __shfl(pk2[mi][2 * kc2 + 1][1], lB);
          u32x4 u;
          u[0] = hiT ? b0 : a0;
          u[1] = hiT ? b1 : a1;
          u[2] = hiT ? b2 : a2;
          u[3] = hiT ? b3 : a3;
          af[mi] = __builtin_bit_cast(f16x8, u);
        }
#pragma unroll
        for (int nt = 0; nt < 4; nt++) {
          f16x8 vf = *(const f16x8*)&Vs[nt * 16 + l16][c * 64 + kc2 * 32 + qd * 8];
          Oa[0][nt] = MFMA16F16(af[0], vf, Oa[0][nt]);
          Oa[1][nt] = MFMA16F16(af[1], vf, Oa[1][nt]);
        }
      }
    }

    // constant positional region: whole tile is tab[100]
    if (j0 + 228 <= q0) {
#pragma unroll
      for (int kc = 0; kc < 4; kc++)
#pragma unroll
        for (int nt = 0; nt < 4; nt++) {
          f16x8 vf = *(const f16x8*)&Vs[nt * 16 + l16][kc * 32 + qd * 8];
          Opc[nt] = MFMA16F16(cf, vf, Opc[nt]);
        }
    }
  }

  // scale attention by (1-w)/l and fold in const-P (row-independent)
#pragma unroll
  for (int mi = 0; mi < 2; mi++) {
    float lr[4];
#pragma unroll
    for (int r = 0; r < 4; r++) lr[r] = __shfl(lrow[mi], qd * 4 + r);
#pragma unroll
    for (int nt = 0; nt < 4; nt++)
#pragma unroll
      for (int r = 0; r < 4; r++)
        Oa[mi][nt][r] = Oa[mi][nt][r] * (one_m_w / lr[r]) + Opc[nt][r];
  }

  // near-diagonal positional band: restage the two boundary V tiles, table fragments
#pragma unroll
  for (int tb = 0; tb < 2; tb++) {
    const int jb = qblk - 128 + tb * 128;  // block-uniform
    if (jb >= 0) {
      __syncthreads();
#pragma unroll
      for (int u = 0; u < 4; u++) {
        const int d = sr16 + u * 16;
        *(f16x8*)&Vs[d][sp16 * 8] =
            *(const f16x8*)(Vt + (size_t)(h * 64 + d) * kM + bt0 + jb + sp16 * 8);
      }
      __syncthreads();
#pragma unroll
      for (int kc = 0; kc < 4; kc++) {
        f16x8 wf[2];
#pragma unroll
        for (int mi = 0; mi < 2; mi++) {
          const int q = q0 + mi * 16 + l16;
#pragma unroll
          for (int jj = 0; jj < 8; jj++) {
            const int j = jb + kc * 32 + qd * 8 + jj;
            const int dlt = q - j;
            float pv = 0.0f;
            if (dlt > 0) pv = tab_s[dlt > kMAXL ? kMAXL : dlt];
            wf[mi][jj] = (f16)pv;
          }
        }
#pragma unroll
        for (int nt = 0; nt < 4; nt++) {
          f16x8 vf = *(const f16x8*)&Vs[nt * 16 + l16][kc * 32 + qd * 8];
          Oa[0][nt] = MFMA16F16(wf[0], vf, Oa[0][nt]);
          Oa[1][nt] = MFMA16F16(wf[1], vf, Oa[1][nt]);
        }
      }
    }
  }

  // store
#pragma unroll
  for (int mi = 0; mi < 2; mi++)
#pragma unroll
    for (int nt = 0; nt < 4; nt++)
#pragma unroll
      for (int r = 0; r < 4; r++) {
        const int q = q0 + mi * 16 + qd * 4 + r;
        Pb[(bt0 + q) * kD + h * 64 + nt * 16 + l16] = (f16)Oa[mi][nt][r];
      }
}

extern "C" void kernel_launch(void* const* d_in, const int* in_sizes, int n_in, void* d_out,
                              int out_size, void* d_ws, size_t ws_size, hipStream_t stream) {
  const float* x = (const float*)d_in[0];
  const float* mu = (const float*)d_in[1];
  const float* lam = (const float*)d_in[2];
  const float* g1 = (const float*)d_in[3];
  const float* g2 = (const float*)d_in[4];
  const float* th1 = (const float*)d_in[5];
  const float* th2 = (const float*)d_in[6];
  const float* Wq = (const float*)d_in[7];
  const float* bq = (const float*)d_in[8];
  const float* Wk = (const float*)d_in[9];
  const float* bk = (const float*)d_in[10];
  const float* Wv = (const float*)d_in[11];
  const float* bv = (const float*)d_in[12];
  const float* Wf = (const float*)d_in[13];
  const float* bf = (const float*)d_in[14];

  if (ws_size < WS_NEED) return;  // cannot run without scratch

  char* ws = (char*)d_ws;
  float* tab = (float*)(ws + OFF_TAB);
  f16* xh = (f16*)(ws + OFF_XH);
  f16* wqh = (f16*)(ws + OFF_WQ);
  f16* wkh = (f16*)(ws + OFF_WK);
  f16* wvh = (f16*)(ws + OFF_WV);
  f16* wfh = (f16*)(ws + OFF_WF);
  f16* Qp = (f16*)(ws + OFF_Q);
  f16* Kp = (f16*)(ws + OFF_K);
  f16* Vtp = (f16*)(ws + OFF_V);
  f16* Pbp = (f16*)(ws + OFF_P);

  mk_tab_kernel<<<1, 256, 0, stream>>>(mu, lam, g1, g2, th1, th2, tab);
  cvt_kernel<<<2048, 256, 0, stream>>>(x, xh, kM * kD / 4);
  cvt_kernel<<<1024, 256, 0, stream>>>(Wq, wqh, kD * kD / 4);
  cvt_kernel<<<1024, 256, 0, stream>>>(Wk, wkh, kD * kD / 4);
  cvt_kernel<<<1024, 256, 0, stream>>>(Wv, wvh, kD * kD / 4);
  cvt_kernel<<<1024, 256, 0, stream>>>(Wf, wfh, kD * kD / 4);

  // Q scaled by log2(e) (after bias) so attention softmax uses exp2 exactly.
  gemm_bt_kernel<f16, false><<<512, 256, 0, stream>>>(xh, wqh, bq, Qp, kM, kD, kD, kLOG2E);
  gemm_bt_kernel<f16, false><<<512, 256, 0, stream>>>(xh, wkh, bk, Kp, kM, kD, kD, 1.0f);
  // V^T = Wv * x^T : same kernel, swapped operands, bias indexed by row (dim)
  gemm_bt_kernel<f16, true><<<512, 256, 0, stream>>>(wvh, xh, bv, Vtp, kD, kM, kD, 1.0f);

  attn_kernel<<<1024, 256, 0, stream>>>(Qp, Kp, Vtp, tab, Pbp);

  gemm_bt_kernel<float, false><<<512, 256, 0, stream>>>(Pbp, wfh, bf, (float*)d_out, kM, kD, kD,
                                                        1.0f);
}